// Round 1
// baseline (2048.398 us; speedup 1.0000x reference)
//
#include <hip/hip_runtime.h>
#include <math.h>

namespace {

constexpr int NN = 100000;   // nodes
constexpr int EE = 1600000;  // edges (without self loops)
constexpr int ET = EE + NN;  // edges + self loops
constexpr float SLOPE = 0.2f;
constexpr float EPS_F = 1e-16f;

__device__ __forceinline__ float atomicMaxFloat(float* addr, float v) {
    // Works for all finite floats given init to -inf:
    // non-negative floats ordered as signed ints; negative floats reverse-ordered as unsigned.
    if (v >= 0.f)
        return __int_as_float(atomicMax((int*)addr, __float_as_int(v)));
    else
        return __uint_as_float(atomicMin((unsigned int*)addr, __float_as_uint(v)));
}

// h = x @ W  (W staged in LDS), fused per-node attention dots:
// alpha_s[n] = dot(h[n], a_src), alpha_d[n] = dot(h[n], a_dst)
template <int IN, int OUT, int NPB>
__global__ __launch_bounds__(256) void gemm_alpha(
    const float* __restrict__ x, const float* __restrict__ W,
    const float* __restrict__ avs, const float* __restrict__ avd,
    float* __restrict__ h, float* __restrict__ alps, float* __restrict__ alpd) {
    static_assert(OUT * NPB == 256, "block layout");
    __shared__ float Wl[IN * OUT];
    __shared__ float xl[NPB * IN];
    const int tid = threadIdx.x;
    for (int i = tid; i < IN * OUT; i += 256) Wl[i] = W[i];
    const int n0 = blockIdx.x * NPB;
    for (int i = tid; i < NPB * IN; i += 256) {
        int n = n0 + i / IN;
        xl[i] = (n < NN) ? x[(size_t)n * IN + (i % IN)] : 0.f;
    }
    __syncthreads();
    const int c = tid % OUT;   // out channel
    const int ny = tid / OUT;  // node within block
    const int n = n0 + ny;
    float acc = 0.f;
#pragma unroll 4
    for (int k = 0; k < IN; ++k) acc += xl[ny * IN + k] * Wl[k * OUT + c];
    if (n < NN) h[(size_t)n * OUT + c] = acc;
    // reduce across the OUT channel lanes (OUT = 32 or 64, both within one wave segment)
    float vs = acc * avs[c];
    float vd = acc * avd[c];
#pragma unroll
    for (int off = OUT / 2; off > 0; off >>= 1) {
        vs += __shfl_down(vs, off, OUT);
        vd += __shfl_down(vd, off, OUT);
    }
    if (c == 0 && n < NN) {
        alps[n] = vs;
        alpd[n] = vd;
    }
}

__global__ __launch_bounds__(256) void init_minf(float* __restrict__ m) {
    int i = blockIdx.x * 256 + threadIdx.x;
    if (i < NN) m[i] = -INFINITY;
}

// Pass over edges: e = leaky_relu(alpha_s[src] + alpha_d[dst]); segment max by dst.
__global__ __launch_bounds__(256) void edge_logits(
    const int* __restrict__ ei, const float* __restrict__ alps,
    const float* __restrict__ alpd, float* __restrict__ ebuf, float* __restrict__ m) {
    int e = blockIdx.x * 256 + threadIdx.x;
    if (e >= ET) return;
    int s, d;
    if (e < EE) {
        s = ei[e];
        d = ei[EE + e];
    } else {
        s = d = e - EE;  // self loop
    }
    float v = alps[s] + alpd[d];
    v = (v >= 0.f) ? v : SLOPE * v;
    ebuf[e] = v;
    atomicMaxFloat(&m[d], v);
}

// Pass over edges: e = exp(e - m[dst]); segment sum by dst.
__global__ __launch_bounds__(256) void edge_exp(
    const int* __restrict__ ei, const float* __restrict__ m,
    float* __restrict__ ebuf, float* __restrict__ denom) {
    int e = blockIdx.x * 256 + threadIdx.x;
    if (e >= ET) return;
    int d = (e < EE) ? ei[EE + e] : (e - EE);
    float v = expf(ebuf[e] - m[d]);
    ebuf[e] = v;
    atomicAdd(&denom[d], v);
}

// Weighted scatter-aggregate: agg[dst][c] += (e / (denom[dst]+eps)) * h[src][c]
// channel-fastest thread layout -> per-(sub)wave contiguous gather + atomic burst.
template <int OUT>
__global__ __launch_bounds__(256) void scatter_agg(
    const int* __restrict__ ei, const float* __restrict__ ebuf,
    const float* __restrict__ denom, const float* __restrict__ h,
    float* __restrict__ agg) {
    unsigned int t = blockIdx.x * 256u + threadIdx.x;
    unsigned int e = t / OUT;
    unsigned int c = t % OUT;
    if (e >= (unsigned int)ET) return;
    int s, d;
    if (e < (unsigned int)EE) {
        s = ei[e];
        d = ei[EE + e];
    } else {
        s = d = (int)e - EE;
    }
    float coef = ebuf[e] / (denom[d] + EPS_F);
    atomicAdd(&agg[(size_t)d * OUT + c], coef * h[(size_t)s * OUT + c]);
}

template <int OUT>
__global__ __launch_bounds__(256) void bias_relu(
    const float* __restrict__ agg, const float* __restrict__ b, float* __restrict__ out) {
    int i = blockIdx.x * 256 + threadIdx.x;
    if (i >= NN * OUT) return;
    float v = agg[i] + b[i & (OUT - 1)];
    out[i] = (v > 0.f) ? v : 0.f;
}

// out[n][c] = relu_h3[n][:] @ Wl[:][c] + bl[c]; 64-node x 64-channel tiles,
// 4x4 register blocking per thread.
__global__ __launch_bounds__(256) void final_linear(
    const float* __restrict__ h, const float* __restrict__ W,
    const float* __restrict__ b, float* __restrict__ out) {
    __shared__ __align__(16) float Wt[64 * 64];  // [k][c]
    __shared__ __align__(16) float hl[64 * 64];  // [n][k]
    const int tid = threadIdx.x;
    const int n0 = blockIdx.x * 64;
    const int c0 = blockIdx.y * 64;
    for (int i = tid; i < 4096; i += 256) {
        int k = i >> 6, c = i & 63;
        Wt[i] = W[k * 512 + c0 + c];
    }
    for (int i = tid; i < 4096; i += 256) {
        int n = i >> 6, k = i & 63;
        int gn = n0 + n;
        hl[i] = (gn < NN) ? h[(size_t)gn * 64 + k] : 0.f;
    }
    __syncthreads();
    const int tc = (tid & 15) * 4;  // 4 consecutive channels
    const int tn = (tid >> 4) * 4;  // 4 nodes
    float acc[4][4] = {};
#pragma unroll 4
    for (int k = 0; k < 64; ++k) {
        float4 wv = *(const float4*)&Wt[k * 64 + tc];
        float h0 = hl[(tn + 0) * 64 + k];
        float h1 = hl[(tn + 1) * 64 + k];
        float h2 = hl[(tn + 2) * 64 + k];
        float h3 = hl[(tn + 3) * 64 + k];
        acc[0][0] += h0 * wv.x; acc[0][1] += h0 * wv.y; acc[0][2] += h0 * wv.z; acc[0][3] += h0 * wv.w;
        acc[1][0] += h1 * wv.x; acc[1][1] += h1 * wv.y; acc[1][2] += h1 * wv.z; acc[1][3] += h1 * wv.w;
        acc[2][0] += h2 * wv.x; acc[2][1] += h2 * wv.y; acc[2][2] += h2 * wv.z; acc[2][3] += h2 * wv.w;
        acc[3][0] += h3 * wv.x; acc[3][1] += h3 * wv.y; acc[3][2] += h3 * wv.z; acc[3][3] += h3 * wv.w;
    }
    float4 bv = *(const float4*)&b[c0 + tc];
#pragma unroll
    for (int j = 0; j < 4; ++j) {
        int gn = n0 + tn + j;
        if (gn < NN) {
            float4 o;
            o.x = acc[j][0] + bv.x;
            o.y = acc[j][1] + bv.y;
            o.z = acc[j][2] + bv.z;
            o.w = acc[j][3] + bv.w;
            *(float4*)&out[(size_t)gn * 512 + c0 + tc] = o;
        }
    }
}

template <int IN, int OUT, int NPB>
void run_gat_layer(const float* x, const float* W, const float* avs, const float* avd,
                   const float* bias, const int* ei, float* hbuf, float* aggbuf,
                   float* ebuf, float* asb, float* adb, float* mb, float* db,
                   hipStream_t stream) {
    gemm_alpha<IN, OUT, NPB><<<(NN + NPB - 1) / NPB, 256, 0, stream>>>(
        x, W, avs, avd, hbuf, asb, adb);
    init_minf<<<(NN + 255) / 256, 256, 0, stream>>>(mb);
    hipMemsetAsync(db, 0, NN * sizeof(float), stream);
    hipMemsetAsync(aggbuf, 0, (size_t)NN * OUT * sizeof(float), stream);
    edge_logits<<<(ET + 255) / 256, 256, 0, stream>>>(ei, asb, adb, ebuf, mb);
    edge_exp<<<(ET + 255) / 256, 256, 0, stream>>>(ei, mb, ebuf, db);
    scatter_agg<OUT><<<((size_t)ET * OUT + 255) / 256, 256, 0, stream>>>(
        ei, ebuf, db, hbuf, aggbuf);
    bias_relu<OUT><<<(NN * OUT + 255) / 256, 256, 0, stream>>>(aggbuf, bias, aggbuf);
}

}  // namespace

extern "C" void kernel_launch(void* const* d_in, const int* in_sizes, int n_in,
                              void* d_out, int out_size, void* d_ws, size_t ws_size,
                              hipStream_t stream) {
    const float* x = (const float*)d_in[0];
    const int* ei = (const int*)d_in[1];  // [2, E] int32 (jax default: x64 disabled)
    const float* W1 = (const float*)d_in[3];
    const float* as1 = (const float*)d_in[4];
    const float* ad1 = (const float*)d_in[5];
    const float* b1 = (const float*)d_in[6];
    const float* W2 = (const float*)d_in[7];
    const float* as2 = (const float*)d_in[8];
    const float* ad2 = (const float*)d_in[9];
    const float* b2 = (const float*)d_in[10];
    const float* W3 = (const float*)d_in[11];
    const float* as3 = (const float*)d_in[12];
    const float* ad3 = (const float*)d_in[13];
    const float* b3 = (const float*)d_in[14];
    const float* Wl = (const float*)d_in[15];
    const float* bl = (const float*)d_in[16];
    float* out = (float*)d_out;

    // workspace layout (floats)
    float* ws = (float*)d_ws;
    float* hbuf = ws;                          // N*64
    float* aggbuf = hbuf + (size_t)NN * 64;    // N*64
    float* ebuf = aggbuf + (size_t)NN * 64;    // ET
    float* asb = ebuf + ET;                    // N
    float* adb = asb + NN;                     // N
    float* mb = adb + NN;                      // N
    float* db = mb + NN;                       // N

    // Layer 1: 128 -> 32
    run_gat_layer<128, 32, 8>(x, W1, as1, ad1, b1, ei, hbuf, aggbuf, ebuf, asb, adb, mb, db, stream);
    // Layer 2: 32 -> 64 (x = aggbuf from layer 1)
    run_gat_layer<32, 64, 4>(aggbuf, W2, as2, ad2, b2, ei, hbuf, aggbuf, ebuf, asb, adb, mb, db, stream);
    // Layer 3: 64 -> 64
    run_gat_layer<64, 64, 4>(aggbuf, W3, as3, ad3, b3, ei, hbuf, aggbuf, ebuf, asb, adb, mb, db, stream);
    // Final linear: 64 -> 512
    dim3 grid((NN + 63) / 64, 8);
    final_linear<<<grid, 256, 0, stream>>>(aggbuf, Wl, bl, out);
}